// Round 7
// baseline (1008.397 us; speedup 1.0000x reference)
//
#include <hip/hip_runtime.h>
#include <cstdint>
#include <cstddef>

typedef __attribute__((ext_vector_type(8))) __bf16 bf16x8;
typedef __attribute__((ext_vector_type(4))) float f32x4;

__device__ __forceinline__ float sigm(float v) { return 1.0f / (1.0f + expf(-v)); }

__device__ __forceinline__ float gelu_fast(float v) {
  float u = v * (1.0f + 0.044715f * v * v);
  float z = 1.5957691216057308f * u;
  return v / (1.0f + __expf(-z));
}

__device__ __forceinline__ void async16(__bf16* lds, const __bf16* g) {
  __builtin_amdgcn_global_load_lds(
      (const __attribute__((address_space(1))) void*)g,
      (__attribute__((address_space(3))) void*)lds, 16, 0, 0);
}

// ---------------- convert fp32 -> bf16, 8 elems/thread ----------------
__global__ __launch_bounds__(256) void k_convert(const float* __restrict__ src,
                                                 __bf16* __restrict__ dst, int n8) {
  int i = blockIdx.x * 256 + threadIdx.x;
  if (i >= n8) return;
  const f32x4* s4 = (const f32x4*)src;
  f32x4 a = s4[2 * i], b = s4[2 * i + 1];
  bf16x8 o;
#pragma unroll
  for (int e = 0; e < 4; ++e) { o[e] = (__bf16)a[e]; o[4 + e] = (__bf16)b[e]; }
  ((bf16x8*)dst)[i] = o;
}

__global__ __launch_bounds__(256) void k_bcat(const float* __restrict__ bh,
                                              const float* __restrict__ bw,
                                              const float* __restrict__ bs,
                                              float* __restrict__ bcat) {
  int i = blockIdx.x * 256 + threadIdx.x;
  if (i >= 2304) return;
  bcat[i] = i < 768 ? bh[i] : (i < 1536 ? bw[i - 768] : bs[i - 1536]);
}

// transpose + convert: src (R x C) fp32 -> dst (C x R) bf16
__global__ __launch_bounds__(256) void k_transpose_cvt(const float* __restrict__ src,
                                                       __bf16* __restrict__ dst,
                                                       int R, int C) {
  __shared__ float t[32][33];
  const int c0 = blockIdx.x * 32, r0 = blockIdx.y * 32;
  const int tx = threadIdx.x, ty = threadIdx.y;  // 32 x 8
#pragma unroll
  for (int i = 0; i < 32; i += 8)
    if (r0 + ty + i < R && c0 + tx < C) t[ty + i][tx] = src[(size_t)(r0 + ty + i) * C + c0 + tx];
  __syncthreads();
#pragma unroll
  for (int i = 0; i < 32; i += 8)
    if (c0 + ty + i < C && r0 + tx < R)
      dst[(size_t)(c0 + ty + i) * R + r0 + tx] = (__bf16)t[tx][ty + i];
}

// b2 = proj_b + P . mixall_b
__global__ __launch_bounds__(256) void k_b2(const float* __restrict__ P,
                                            const float* __restrict__ bm,
                                            const float* __restrict__ pb,
                                            float* __restrict__ b2) {
  const int d = blockIdx.x * 256 + threadIdx.x;
  if (d >= 768) return;
  float acc = pb[d];
  const float* row = P + (size_t)d * 768;
#pragma unroll 4
  for (int c = 0; c < 768; c += 4) {
    f32x4 p4 = *(const f32x4*)(row + c);
    f32x4 b4 = *(const f32x4*)(bm + c);
    acc += p4[0] * b4[0] + p4[1] * b4[1] + p4[2] * b4[2] + p4[3] * b4[3];
  }
  b2[d] = acc;
}

// ===== 256x128 GEMM (BT layout), BK=32, 4 waves of 128x64 (8x4 frags), ring-3 LDS =====
// A: MxK K-contig (M%256==0), B: NxK K-contig (N%128==0), K%96==0 for EPI4 else %32.
// 72KB LDS, 2 blocks/CU (128 AGPR + ~100 VGPR = 228 regs -> needs (256,2); (256,3)
// spills acc to scratch: R6 measured 1GB/dispatch scratch writes, 3x slowdown).
// Swizzle (both-sides, rule #21): 16B chunk ch ^= (row>>1)&3 -> conflict-free
// (R6: SQ_LDS_BANK_CONFLICT = 0) and coalesced (64B per 4 lanes).
// Per phase: {stage(t+2): 6 gload_lds; 12 ds_read_b128; 32 MFMA; vmcnt(6); barrier}.
// EPI 0: out_bf16 = gelu(acc + bias[col])
// EPI 3: out_bf16 = acc
// EPI 4 (final GEMM, gates fused): A thirds: S1 (k<K/3) from A, S2 from A,
//   S3 (k>=2K/3) from pre-gated A2 (stride 768). acc *= ghr/ghwr after K/3,
//   acc *= ghwr after 2K/3  ->  acc = gh*S1 + ghw*S2 + S3g.
//   out_f32 = g0*(acc + bias[col]) + g1*xres.
template <int EPI>
__global__ __launch_bounds__(256, 2) void k_gemm(
    const __bf16* __restrict__ A, const __bf16* __restrict__ B,
    const float* __restrict__ bias, __bf16* __restrict__ outB,
    float* __restrict__ outF, const float* __restrict__ xres,
    const float* __restrict__ gatew, int N, int K,
    const __bf16* __restrict__ A2, const float* __restrict__ ghr,
    const float* __restrict__ ghwr) {
  __shared__ __bf16 lds[36864];  // 3 x (A 256x32 + B 128x32)
  const int tid = threadIdx.x;
  const int lane = tid & 63, wid = tid >> 6;
  const int wr = wid >> 1, wc = wid & 1;  // 2x2 wave grid, wave out 128x64

  // bijective XCD swizzle (m204), tn-inner for A-panel L2 reuse
  const int nwg = gridDim.x;
  const int q = nwg >> 3, r = nwg & 7;
  const int xcd = blockIdx.x & 7, bidx = blockIdx.x >> 3;
  const int wgid = (xcd < r ? xcd * (q + 1) : r * (q + 1) + (xcd - r) * q) + bidx;
  const int nTn = N >> 7;
  const int tm = wgid / nTn, tn = wgid % nTn;

  const __bf16* Ag = A + (size_t)tm * 256 * K;
  const __bf16* A2g = (EPI == 4) ? A2 + (size_t)tm * 256 * 768 : nullptr;
  const __bf16* Bg = B + (size_t)tn * 128 * K;

  const int NT = K >> 5;
  const int tb1 = NT / 3, tb2 = (2 * NT) / 3;  // EPI4 third-boundaries (in tiles)

  // stage K-tile kt into ring buf: A 256x32 (4 loads/thr), B 128x32 (2 loads/thr)
  auto stage = [&](int buf, int kt) {
    const int base = buf * 12288;
    const bool useA2 = (EPI == 4) && (kt >= tb2);
#pragma unroll
    for (int j = 0; j < 4; ++j) {
      const int lin = j * 256 + tid;
      const int row = lin >> 2, ch = lin & 3;
      const int sc = (ch ^ ((row >> 1) & 3)) << 3;
      const __bf16* src = useA2
          ? A2g + (size_t)row * 768 + (kt - tb2) * 32 + sc
          : Ag + (size_t)row * K + kt * 32 + sc;
      async16(&lds[base + lin * 8], src);
    }
#pragma unroll
    for (int j = 0; j < 2; ++j) {
      const int lin = j * 256 + tid;
      const int row = lin >> 2, ch = lin & 3;
      async16(&lds[base + 8192 + lin * 8],
              Bg + (size_t)row * K + kt * 32 + ((ch ^ ((row >> 1) & 3)) << 3));
    }
  };

  f32x4 acc[8][4];
#pragma unroll
  for (int m = 0; m < 8; ++m)
#pragma unroll
    for (int n = 0; n < 4; ++n) acc[m][n] = f32x4{0.f, 0.f, 0.f, 0.f};

  const int kc = lane >> 4;              // k-chunk 0..3
  const int rA = wr * 128 + (lane & 15); // +m*16 keeps (row>>1)&3
  const int rB = wc * 64 + (lane & 15);
  const int chA = kc ^ ((rA >> 1) & 3);
  const int chB = kc ^ ((rB >> 1) & 3);
  const int orow = (lane >> 4) * 4;

  stage(0, 0);
  stage(1, 1);
  asm volatile("s_waitcnt vmcnt(6)" ::: "memory");
  __builtin_amdgcn_s_barrier();

  for (int t = 0; t < NT; ++t) {
    const int cb = (t % 3) * 12288;
    if (t + 2 < NT) stage((t + 2) % 3, t + 2);  // prefetch first
    bf16x8 af[8], bfv[4];
#pragma unroll
    for (int m = 0; m < 8; ++m)
      af[m] = *(const bf16x8*)&lds[cb + (rA + m * 16) * 32 + chA * 8];
#pragma unroll
    for (int n = 0; n < 4; ++n)
      bfv[n] = *(const bf16x8*)&lds[cb + 8192 + (rB + n * 16) * 32 + chB * 8];
    __builtin_amdgcn_s_setprio(1);
#pragma unroll
    for (int m = 0; m < 8; ++m)
#pragma unroll
      for (int n = 0; n < 4; ++n)
        acc[m][n] = __builtin_amdgcn_mfma_f32_16x16x32_bf16(af[m], bfv[n], acc[m][n], 0, 0, 0);
    __builtin_amdgcn_s_setprio(0);
    if constexpr (EPI == 4) {
      // fold per-row h/w gates into acc at third-boundaries (uniform branch)
      if (t == tb1 - 1) {
#pragma unroll
        for (int m = 0; m < 8; ++m)
#pragma unroll
          for (int rr = 0; rr < 4; ++rr) {
            const int rg = tm * 256 + wr * 128 + m * 16 + orow + rr;
            const float f = ghr[rg] / ghwr[rg];
#pragma unroll
            for (int n = 0; n < 4; ++n) acc[m][n][rr] *= f;
          }
      } else if (t == tb2 - 1) {
#pragma unroll
        for (int m = 0; m < 8; ++m)
#pragma unroll
          for (int rr = 0; rr < 4; ++rr) {
            const int rg = tm * 256 + wr * 128 + m * 16 + orow + rr;
            const float f = ghwr[rg];
#pragma unroll
            for (int n = 0; n < 4; ++n) acc[m][n][rr] *= f;
          }
      }
    }
    if (t + 2 < NT) { asm volatile("s_waitcnt vmcnt(6)" ::: "memory"); }
    else            { asm volatile("s_waitcnt vmcnt(0)" ::: "memory"); }
    __builtin_amdgcn_s_barrier();
  }

  // epilogue: C/D layout col=lane&15, row=(lane>>4)*4+reg  [m89]
  const int ocol = lane & 15;
  float g0 = 0.f, g1 = 0.f;
  if constexpr (EPI == 4) { g0 = gatew[0]; g1 = gatew[1]; }
#pragma unroll
  for (int m = 0; m < 8; ++m) {
#pragma unroll
    for (int n = 0; n < 4; ++n) {
#pragma unroll
      for (int rr = 0; rr < 4; ++rr) {
        const int rg = tm * 256 + wr * 128 + m * 16 + orow + rr;
        const int cg = tn * 128 + wc * 64 + n * 16 + ocol;
        if constexpr (EPI == 0) {
          float v = acc[m][n][rr] + bias[cg];
          outB[(size_t)rg * N + cg] = (__bf16)gelu_fast(v);
        } else if constexpr (EPI == 4) {
          float v = acc[m][n][rr] + bias[cg];
          outF[(size_t)rg * N + cg] = g0 * v + g1 * xres[(size_t)rg * N + cg];
        } else {
          outB[(size_t)rg * N + cg] = (__bf16)acc[m][n][rr];
        }
      }
    }
  }
}

// ---------------- pooling: h2v (B,7), w2v (B,7), s1v (B,768) ----------------
__global__ __launch_bounds__(256) void k_pool(const __bf16* __restrict__ hws,
                                              float* __restrict__ h2v,
                                              float* __restrict__ w2v,
                                              float* __restrict__ s1v) {
  const int b = blockIdx.x, t = threadIdx.x;
  const int lane = t & 63, wave = t >> 6;
  const size_t base = (size_t)b * 49 * 2304;
  float hloc[7], wloc[7];
#pragma unroll
  for (int i = 0; i < 7; ++i) { hloc[i] = 0.f; wloc[i] = 0.f; }
  float sacc[8], sacc2[8];
#pragma unroll
  for (int e = 0; e < 8; ++e) { sacc[e] = 0.f; sacc2[e] = 0.f; }

  const bool isH = t < 96, isW = (t >= 96 && t < 192);
  const int off1 = isH ? t * 8 : (isW ? 768 + (t - 96) * 8 : 1536 + (t - 192) * 8);
  const int off2 = 1536 + (64 + t) * 8;

#pragma unroll
  for (int p = 0; p < 49; ++p) {
    const int hi = p / 7, wi = p % 7;
    const __bf16* row = hws + base + (size_t)p * 2304;
    bf16x8 v = *(const bf16x8*)(row + off1);
    float s8 = 0.f;
#pragma unroll
    for (int e = 0; e < 8; ++e) s8 += (float)v[e];
    if (isH) hloc[hi] += s8;
    else if (isW) wloc[wi] += s8;
    else {
#pragma unroll
      for (int e = 0; e < 8; ++e) sacc[e] += (float)v[e];
    }
    if (t < 32) {
      bf16x8 v2 = *(const bf16x8*)(row + off2);
#pragma unroll
      for (int e = 0; e < 8; ++e) sacc2[e] += (float)v2[e];
    }
  }

  if (t >= 192) {
#pragma unroll
    for (int e = 0; e < 8; ++e)
      s1v[b * 768 + (t - 192) * 8 + e] = sacc[e] * (1.f / 49.f);
  }
  if (t < 32) {
#pragma unroll
    for (int e = 0; e < 8; ++e)
      s1v[b * 768 + 512 + t * 8 + e] = sacc2[e] * (1.f / 49.f);
  }

  __shared__ float red[4][14];
#pragma unroll
  for (int i = 0; i < 7; ++i) {
    float hv = hloc[i], wv = wloc[i];
#pragma unroll
    for (int s = 32; s; s >>= 1) { hv += __shfl_xor(hv, s); wv += __shfl_xor(wv, s); }
    if (lane == 0) { red[wave][i] = hv; red[wave][7 + i] = wv; }
  }
  __syncthreads();
  if (t < 7) {
    h2v[b * 7 + t] = (red[0][t] + red[1][t] + red[2][t] + red[3][t]) * (1.f / 5376.f);
  } else if (t >= 16 && t < 23) {
    const int i = t - 16;
    w2v[b * 7 + i] =
        (red[0][7 + i] + red[1][7 + i] + red[2][7 + i] + red[3][7 + i]) * (1.f / 5376.f);
  }
}

// ---------------- gates: ghr/ghwr (B*49 row-expanded), g_c (B,768) ----------------
__global__ __launch_bounds__(256) void k_gates(
    const float* __restrict__ h2v, const float* __restrict__ w2v,
    const float* __restrict__ s1v, const float* __restrict__ convH_w,
    const float* __restrict__ convH_b, const float* __restrict__ convH2_k,
    const float* __restrict__ convH2_b, const float* __restrict__ mixhw_k,
    const float* __restrict__ mixhw_b, const float* __restrict__ mixhw2_k,
    const float* __restrict__ mixhw2_b, const float* __restrict__ mixhws_k,
    const float* __restrict__ mixhws_b, const float* __restrict__ mixhws2_k,
    const float* __restrict__ mixhws2_b, const float* __restrict__ linHW,
    const float* __restrict__ linHb, const float* __restrict__ linWW,
    const float* __restrict__ linWb, float* __restrict__ ghr,
    float* __restrict__ ghwr, float* __restrict__ g_c) {
  const int b = blockIdx.x, t = threadIdx.x;
  __shared__ float hv[7], wv[7];
  __shared__ float ghs[7], ghws[7];
  __shared__ float tc[770];
  if (t < 7) { hv[t] = h2v[b * 7 + t]; wv[t] = w2v[b * 7 + t]; }
  if (t == 7) { tc[0] = 0.f; tc[769] = 0.f; }
  __syncthreads();

  if (t < 7) {
    const float cw = convH_w[0], cbv = convH_b[0];
    const float k0 = convH2_k[0], k1 = convH2_k[1], k2 = convH2_k[2], b2 = convH2_b[0];
    const float um = t > 0 ? sigm(hv[t - 1] * cw + cbv) : 0.f;
    const float u0 = sigm(hv[t] * cw + cbv);
    const float up = t < 6 ? sigm(hv[t + 1] * cw + cbv) : 0.f;
    ghs[t] = sigm(k0 * um + k1 * u0 + k2 * up + b2);

    const float a0 = mixhw_k[0], a1 = mixhw_k[1], ab = mixhw_b[0];
    const float q0 = mixhw2_k[0], q1 = mixhw2_k[1], q2 = mixhw2_k[2], qb = mixhw2_b[0];
    const float vm = t > 0 ? sigm(a0 * hv[t - 1] + a1 * wv[t - 1] + ab) : 0.f;
    const float v0 = sigm(a0 * hv[t] + a1 * wv[t] + ab);
    const float vp = t < 6 ? sigm(a0 * hv[t + 1] + a1 * wv[t + 1] + ab) : 0.f;
    ghws[t] = sigm(q0 * vm + q1 * v0 + q2 * vp + qb);
  }

  const float m0 = mixhws_k[0], m1 = mixhws_k[1], m2 = mixhws_k[2], mb = mixhws_b[0];
#pragma unroll
  for (int j = 0; j < 3; ++j) {
    const int c = t + j * 256;
    float h2l = linHb[c], w2l = linWb[c];
#pragma unroll
    for (int i = 0; i < 7; ++i) {
      h2l += hv[i] * linHW[c * 7 + i];
      w2l += wv[i] * linWW[c * 7 + i];
    }
    tc[1 + c] = sigm(m0 * h2l + m1 * w2l + m2 * s1v[b * 768 + c] + mb);
  }
  __syncthreads();
  const float r0 = mixhws2_k[0], r1 = mixhws2_k[1], r2 = mixhws2_k[2], rb2 = mixhws2_b[0];
#pragma unroll
  for (int j = 0; j < 3; ++j) {
    const int c = t + j * 256;
    g_c[b * 768 + c] = sigm(r0 * tc[c] + r1 * tc[c + 1] + r2 * tc[c + 2] + rb2);
  }
  if (t < 49) {  // row-expanded gates for GEMM2's acc-rescale
    ghr[b * 49 + t] = ghs[t / 7];
    ghwr[b * 49 + t] = ghws[t % 7];
  }
}

// ---------------- gate s-third into separate buffer (pre-GEMM2 A2) ----------------
__global__ __launch_bounds__(256) void k_gapply_s(const __bf16* __restrict__ hws,
                                                  const float* __restrict__ g_c,
                                                  __bf16* __restrict__ sg) {
  const int idx = blockIdx.x * 256 + threadIdx.x;  // chunk of 8 bf16; 25088*96 total
  const int c8 = idx % 96;
  const int r = idx / 96;
  const int b = r / 49;
  bf16x8 v = *(const bf16x8*)(hws + (size_t)r * 2304 + 1536 + c8 * 8);
  const float* gcp = g_c + b * 768 + c8 * 8;
  f32x4 gA = *(const f32x4*)gcp;
  f32x4 gB = *(const f32x4*)(gcp + 4);
  bf16x8 o;
#pragma unroll
  for (int e = 0; e < 4; ++e) {
    o[e] = (__bf16)((float)v[e] * gA[e]);
    o[4 + e] = (__bf16)((float)v[4 + e] * gB[e]);
  }
  ((bf16x8*)sg)[idx] = o;
}

// ---------------- launch ----------------
extern "C" void kernel_launch(void* const* d_in, const int* in_sizes, int n_in,
                              void* d_out, int out_size, void* d_ws, size_t ws_size,
                              hipStream_t stream) {
  const float* x        = (const float*)d_in[0];
  const float* Wh       = (const float*)d_in[1];
  const float* bh       = (const float*)d_in[2];
  const float* Ww       = (const float*)d_in[3];
  const float* bw       = (const float*)d_in[4];
  const float* Ws       = (const float*)d_in[5];
  const float* bs       = (const float*)d_in[6];
  const float* convH_w  = (const float*)d_in[7];
  const float* convH_b  = (const float*)d_in[8];
  const float* convH2_k = (const float*)d_in[9];
  const float* convH2_b = (const float*)d_in[10];
  const float* mixhw_k  = (const float*)d_in[11];
  const float* mixhw_b  = (const float*)d_in[12];
  const float* mixhw2_k = (const float*)d_in[13];
  const float* mixhw2_b = (const float*)d_in[14];
  const float* mixhws_k = (const float*)d_in[15];
  const float* mixhws_b = (const float*)d_in[16];
  const float* mixhws2_k= (const float*)d_in[17];
  const float* mixhws2_b= (const float*)d_in[18];
  const float* linHW    = (const float*)d_in[19];
  const float* linHb    = (const float*)d_in[20];
  const float* linWW    = (const float*)d_in[21];
  const float* linWb    = (const float*)d_in[22];
  const float* mixallW  = (const float*)d_in[23];
  const float* mixallb  = (const float*)d_in[24];
  const float* projW    = (const float*)d_in[25];
  const float* projb    = (const float*)d_in[26];
  const float* gatew    = (const float*)d_in[27];
  float* out = (float*)d_out;
  (void)in_sizes; (void)n_in; (void)out_size; (void)ws_size;

  const int M = 25088;  // 512*7*7
  char* ws = (char*)d_ws;
  size_t off = 0;
  auto carve = [&](size_t bytes) -> void* {
    void* p = ws + off;
    off += (bytes + 255) & ~(size_t)255;
    return p;
  };
  __bf16* xb     = (__bf16*)carve((size_t)M * 768 * 2);
  __bf16* Wcat   = (__bf16*)carve((size_t)2304 * 768 * 2);
  __bf16* Pb     = (__bf16*)carve((size_t)768 * 768 * 2);
  __bf16* Dt     = (__bf16*)carve((size_t)2304 * 768 * 2);
  __bf16* W2     = (__bf16*)carve((size_t)768 * 2304 * 2);
  float*  bcat   = (float*)carve(2304 * 4);
  float*  b2     = (float*)carve(768 * 4);
  __bf16* hws    = (__bf16*)carve((size_t)M * 2304 * 2);
  __bf16* sg     = (__bf16*)carve((size_t)M * 768 * 2);
  float*  h2v    = (float*)carve(512 * 7 * 4);
  float*  w2v    = (float*)carve(512 * 7 * 4);
  float*  s1v    = (float*)carve(512 * 768 * 4);
  float*  ghr    = (float*)carve((size_t)M * 4);
  float*  ghwr   = (float*)carve((size_t)M * 4);
  float*  gc     = (float*)carve(512 * 768 * 4);

  k_convert<<<9408, 256, 0, stream>>>(x, xb, (M * 768) / 8);
  k_convert<<<288, 256, 0, stream>>>(Wh, Wcat, 73728);
  k_convert<<<288, 256, 0, stream>>>(Ww, Wcat + 589824, 73728);
  k_convert<<<288, 256, 0, stream>>>(Ws, Wcat + 1179648, 73728);
  k_convert<<<288, 256, 0, stream>>>(projW, Pb, 73728);
  k_transpose_cvt<<<dim3(72, 24), dim3(32, 8), 0, stream>>>(mixallW, Dt, 768, 2304);
  k_bcat<<<9, 256, 0, stream>>>(bh, bw, bs, bcat);
  k_b2<<<3, 256, 0, stream>>>(projW, mixallb, projb, b2);

  // W2 = P . D : (768 x 2304), K=768
  k_gemm<3><<<3 * 18, 256, 0, stream>>>(Pb, Dt, nullptr, W2, nullptr, nullptr,
                                        nullptr, 2304, 768, nullptr, nullptr, nullptr);
  // [h|w|s] = gelu(x @ [Wh|Ww|Ws]^T + bcat)   (M x 2304, K=768)
  k_gemm<0><<<98 * 18, 256, 0, stream>>>(xb, Wcat, bcat, hws, nullptr, nullptr,
                                         nullptr, 2304, 768, nullptr, nullptr, nullptr);
  k_pool<<<512, 256, 0, stream>>>(hws, h2v, w2v, s1v);
  k_gates<<<512, 256, 0, stream>>>(h2v, w2v, s1v, convH_w, convH_b, convH2_k,
                                   convH2_b, mixhw_k, mixhw_b, mixhw2_k, mixhw2_b,
                                   mixhws_k, mixhws_b, mixhws2_k, mixhws2_b,
                                   linHW, linHb, linWW, linWb, ghr, ghwr, gc);
  k_gapply_s<<<9408, 256, 0, stream>>>(hws, gc, sg);
  // out = g0*(cat_gated @ W2^T + b2) + g1*x   (M x 768, K=2304, gates fused)
  k_gemm<4><<<98 * 6, 256, 0, stream>>>(hws, W2, b2, nullptr, out, x,
                                        gatew, 768, 2304, sg, ghr, ghwr);
}

// Round 8
// 412.167 us; speedup vs baseline: 2.4466x; 2.4466x over previous
//
#include <hip/hip_runtime.h>
#include <cstdint>
#include <cstddef>

typedef __attribute__((ext_vector_type(8))) __bf16 bf16x8;
typedef __attribute__((ext_vector_type(4))) float f32x4;

__device__ __forceinline__ float sigm(float v) { return 1.0f / (1.0f + expf(-v)); }

__device__ __forceinline__ float gelu_fast(float v) {
  float u = v * (1.0f + 0.044715f * v * v);
  float z = 1.5957691216057308f * u;
  return v / (1.0f + __expf(-z));
}

__device__ __forceinline__ void async16(__bf16* lds, const __bf16* g) {
  __builtin_amdgcn_global_load_lds(
      (const __attribute__((address_space(1))) void*)g,
      (__attribute__((address_space(3))) void*)lds, 16, 0, 0);
}

// ---------------- convert fp32 -> bf16, 8 elems/thread ----------------
__global__ __launch_bounds__(256) void k_convert(const float* __restrict__ src,
                                                 __bf16* __restrict__ dst, int n8) {
  int i = blockIdx.x * 256 + threadIdx.x;
  if (i >= n8) return;
  const f32x4* s4 = (const f32x4*)src;
  f32x4 a = s4[2 * i], b = s4[2 * i + 1];
  bf16x8 o;
#pragma unroll
  for (int e = 0; e < 4; ++e) { o[e] = (__bf16)a[e]; o[4 + e] = (__bf16)b[e]; }
  ((bf16x8*)dst)[i] = o;
}

__global__ __launch_bounds__(256) void k_bcat(const float* __restrict__ bh,
                                              const float* __restrict__ bw,
                                              const float* __restrict__ bs,
                                              float* __restrict__ bcat) {
  int i = blockIdx.x * 256 + threadIdx.x;
  if (i >= 2304) return;
  bcat[i] = i < 768 ? bh[i] : (i < 1536 ? bw[i - 768] : bs[i - 1536]);
}

// transpose + convert: src (R x C) fp32 -> dst (C x R) bf16
__global__ __launch_bounds__(256) void k_transpose_cvt(const float* __restrict__ src,
                                                       __bf16* __restrict__ dst,
                                                       int R, int C) {
  __shared__ float t[32][33];
  const int c0 = blockIdx.x * 32, r0 = blockIdx.y * 32;
  const int tx = threadIdx.x, ty = threadIdx.y;  // 32 x 8
#pragma unroll
  for (int i = 0; i < 32; i += 8)
    if (r0 + ty + i < R && c0 + tx < C) t[ty + i][tx] = src[(size_t)(r0 + ty + i) * C + c0 + tx];
  __syncthreads();
#pragma unroll
  for (int i = 0; i < 32; i += 8)
    if (c0 + ty + i < C && r0 + tx < R)
      dst[(size_t)(c0 + ty + i) * R + r0 + tx] = (__bf16)t[tx][ty + i];
}

// b2 = proj_b + P . mixall_b
__global__ __launch_bounds__(256) void k_b2(const float* __restrict__ P,
                                            const float* __restrict__ bm,
                                            const float* __restrict__ pb,
                                            float* __restrict__ b2) {
  const int d = blockIdx.x * 256 + threadIdx.x;
  if (d >= 768) return;
  float acc = pb[d];
  const float* row = P + (size_t)d * 768;
#pragma unroll 4
  for (int c = 0; c < 768; c += 4) {
    f32x4 p4 = *(const f32x4*)(row + c);
    f32x4 b4 = *(const f32x4*)(bm + c);
    acc += p4[0] * b4[0] + p4[1] * b4[1] + p4[2] * b4[2] + p4[3] * b4[3];
  }
  b2[d] = acc;
}

// ===== BMx128 GEMM (BT layout), BK=32, wave-tile 128x64 (8x4 frags), ring-3 LDS =====
// SMALL=0: BM=256, 4 waves (2x2), 72KB LDS, 2 blocks/CU, 6 loads/stage, vmcnt(6).
// SMALL=1: BM=128, 2 waves (1x2), 48KB LDS, 3 blocks/CU (tail quantum halved:
//          GEMM2 1176 blocks / 768 slots -> 77% tail eff vs 57%), 8 loads/stage,
//          vmcnt(8).
// Register budget (R6/R7 lesson): acc = 128 AGPR + ~100 VGPR = 228 <= 256 at
// 8 waves/CU (SMALL=0) or 6 waves/CU (SMALL=1). Do NOT add in-loop per-row work.
// Swizzle (both-sides, rule #21): 16B chunk ch ^= (row>>1)&3 -> conflict-free
// (R6/R7 measured SQ_LDS_BANK_CONFLICT = 0) and coalesced (64B per 4 lanes).
// Per phase: {stage(t+2); 12 ds_read_b128; 32 MFMA (setprio); vmcnt(L); barrier}.
// vmcnt ledger: L loads/stage; end-of-phase vmcnt(L) retires stage(t+1) (FIFO),
// leaves stage(t+2) in flight. buf[(t+2)%3] overwrite barrier-protected.
// EPI 0: out_bf16 = gelu(acc + bias[col]);  EPI 2: out_f32 = g0*(acc+bias)+g1*xres;
// EPI 3: out_bf16 = acc.
template <int EPI, int SMALL>
__global__ __launch_bounds__(SMALL ? 128 : 256, 2) void k_gemm(
    const __bf16* __restrict__ A, const __bf16* __restrict__ B,
    const float* __restrict__ bias, __bf16* __restrict__ outB,
    float* __restrict__ outF, const float* __restrict__ xres,
    const float* __restrict__ gatew, int N, int K) {
  constexpr int THREADS = SMALL ? 128 : 256;
  constexpr int BM = SMALL ? 128 : 256;
  constexpr int SBUF = SMALL ? 8192 : 12288;   // elems per ring buf
  constexpr int BOFF = SMALL ? 4096 : 8192;    // B-region offset in buf
  constexpr int BJ = SMALL ? 4 : 2;            // B stage loads per thread
  __shared__ __bf16 lds[3 * SBUF];
  const int tid = threadIdx.x;
  const int lane = tid & 63, wid = tid >> 6;
  const int wr = SMALL ? 0 : (wid >> 1);
  const int wc = SMALL ? wid : (wid & 1);

  // bijective XCD swizzle (m204), tn-inner for A-panel L2 reuse
  const int nwg = gridDim.x;
  const int q = nwg >> 3, r = nwg & 7;
  const int xcd = blockIdx.x & 7, bidx = blockIdx.x >> 3;
  const int wgid = (xcd < r ? xcd * (q + 1) : r * (q + 1) + (xcd - r) * q) + bidx;
  const int nTn = N >> 7;
  const int tm = wgid / nTn, tn = wgid % nTn;

  const __bf16* Ag = A + (size_t)tm * BM * K;
  const __bf16* Bg = B + (size_t)tn * 128 * K;

  // stage K-tile kt into ring buf: A BMx32 (4 loads/thr), B 128x32 (BJ loads/thr)
  auto stage = [&](int buf, int kt) {
    const int base = buf * SBUF;
#pragma unroll
    for (int j = 0; j < 4; ++j) {
      const int lin = j * THREADS + tid;
      const int row = lin >> 2, ch = lin & 3;
      async16(&lds[base + lin * 8],
              Ag + (size_t)row * K + kt * 32 + ((ch ^ ((row >> 1) & 3)) << 3));
    }
#pragma unroll
    for (int j = 0; j < BJ; ++j) {
      const int lin = j * THREADS + tid;
      const int row = lin >> 2, ch = lin & 3;
      async16(&lds[base + BOFF + lin * 8],
              Bg + (size_t)row * K + kt * 32 + ((ch ^ ((row >> 1) & 3)) << 3));
    }
  };

  f32x4 acc[8][4];
#pragma unroll
  for (int m = 0; m < 8; ++m)
#pragma unroll
    for (int n = 0; n < 4; ++n) acc[m][n] = f32x4{0.f, 0.f, 0.f, 0.f};

  const int kc = lane >> 4;              // k-chunk 0..3
  const int rA = wr * 128 + (lane & 15); // +m*16 keeps (row>>1)&3
  const int rB = wc * 64 + (lane & 15);
  const int chA = kc ^ ((rA >> 1) & 3);
  const int chB = kc ^ ((rB >> 1) & 3);
  const int NT = K >> 5;

  stage(0, 0);
  stage(1, 1);
  if constexpr (SMALL) { asm volatile("s_waitcnt vmcnt(8)" ::: "memory"); }
  else                 { asm volatile("s_waitcnt vmcnt(6)" ::: "memory"); }
  __builtin_amdgcn_s_barrier();

  for (int t = 0; t < NT; ++t) {
    const int cb = (t % 3) * SBUF;
    if (t + 2 < NT) stage((t + 2) % 3, t + 2);  // prefetch first
    bf16x8 af[8], bfv[4];
#pragma unroll
    for (int m = 0; m < 8; ++m)
      af[m] = *(const bf16x8*)&lds[cb + (rA + m * 16) * 32 + chA * 8];
#pragma unroll
    for (int n = 0; n < 4; ++n)
      bfv[n] = *(const bf16x8*)&lds[cb + BOFF + (rB + n * 16) * 32 + chB * 8];
    __builtin_amdgcn_s_setprio(1);
#pragma unroll
    for (int m = 0; m < 8; ++m)
#pragma unroll
      for (int n = 0; n < 4; ++n)
        acc[m][n] = __builtin_amdgcn_mfma_f32_16x16x32_bf16(af[m], bfv[n], acc[m][n], 0, 0, 0);
    __builtin_amdgcn_s_setprio(0);
    if (t + 2 < NT) {
      if constexpr (SMALL) { asm volatile("s_waitcnt vmcnt(8)" ::: "memory"); }
      else                 { asm volatile("s_waitcnt vmcnt(6)" ::: "memory"); }
    } else {
      asm volatile("s_waitcnt vmcnt(0)" ::: "memory");
    }
    __builtin_amdgcn_s_barrier();
  }

  // epilogue: C/D layout col=lane&15, row=(lane>>4)*4+reg  [m89]
  const int orow = (lane >> 4) * 4;
  const int ocol = lane & 15;
  float g0 = 0.f, g1 = 0.f;
  if constexpr (EPI == 2) { g0 = gatew[0]; g1 = gatew[1]; }
#pragma unroll
  for (int m = 0; m < 8; ++m) {
#pragma unroll
    for (int n = 0; n < 4; ++n) {
#pragma unroll
      for (int rr = 0; rr < 4; ++rr) {
        const int rg = tm * BM + wr * 128 + m * 16 + orow + rr;
        const int cg = tn * 128 + wc * 64 + n * 16 + ocol;
        if constexpr (EPI == 0) {
          float v = acc[m][n][rr] + bias[cg];
          outB[(size_t)rg * N + cg] = (__bf16)gelu_fast(v);
        } else if constexpr (EPI == 2) {
          float v = acc[m][n][rr] + bias[cg];
          outF[(size_t)rg * N + cg] = g0 * v + g1 * xres[(size_t)rg * N + cg];
        } else {
          outB[(size_t)rg * N + cg] = (__bf16)acc[m][n][rr];
        }
      }
    }
  }
}

// ---------------- pooling: h2v (B,7), w2v (B,7), s1v (B,768) ----------------
__global__ __launch_bounds__(256) void k_pool(const __bf16* __restrict__ hws,
                                              float* __restrict__ h2v,
                                              float* __restrict__ w2v,
                                              float* __restrict__ s1v) {
  const int b = blockIdx.x, t = threadIdx.x;
  const int lane = t & 63, wave = t >> 6;
  const size_t base = (size_t)b * 49 * 2304;
  float hloc[7], wloc[7];
#pragma unroll
  for (int i = 0; i < 7; ++i) { hloc[i] = 0.f; wloc[i] = 0.f; }
  float sacc[8], sacc2[8];
#pragma unroll
  for (int e = 0; e < 8; ++e) { sacc[e] = 0.f; sacc2[e] = 0.f; }

  const bool isH = t < 96, isW = (t >= 96 && t < 192);
  const int off1 = isH ? t * 8 : (isW ? 768 + (t - 96) * 8 : 1536 + (t - 192) * 8);
  const int off2 = 1536 + (64 + t) * 8;

#pragma unroll
  for (int p = 0; p < 49; ++p) {
    const int hi = p / 7, wi = p % 7;
    const __bf16* row = hws + base + (size_t)p * 2304;
    bf16x8 v = *(const bf16x8*)(row + off1);
    float s8 = 0.f;
#pragma unroll
    for (int e = 0; e < 8; ++e) s8 += (float)v[e];
    if (isH) hloc[hi] += s8;
    else if (isW) wloc[wi] += s8;
    else {
#pragma unroll
      for (int e = 0; e < 8; ++e) sacc[e] += (float)v[e];
    }
    if (t < 32) {
      bf16x8 v2 = *(const bf16x8*)(row + off2);
#pragma unroll
      for (int e = 0; e < 8; ++e) sacc2[e] += (float)v2[e];
    }
  }

  if (t >= 192) {
#pragma unroll
    for (int e = 0; e < 8; ++e)
      s1v[b * 768 + (t - 192) * 8 + e] = sacc[e] * (1.f / 49.f);
  }
  if (t < 32) {
#pragma unroll
    for (int e = 0; e < 8; ++e)
      s1v[b * 768 + 512 + t * 8 + e] = sacc2[e] * (1.f / 49.f);
  }

  __shared__ float red[4][14];
#pragma unroll
  for (int i = 0; i < 7; ++i) {
    float hv = hloc[i], wv = wloc[i];
#pragma unroll
    for (int s = 32; s; s >>= 1) { hv += __shfl_xor(hv, s); wv += __shfl_xor(wv, s); }
    if (lane == 0) { red[wave][i] = hv; red[wave][7 + i] = wv; }
  }
  __syncthreads();
  if (t < 7) {
    h2v[b * 7 + t] = (red[0][t] + red[1][t] + red[2][t] + red[3][t]) * (1.f / 5376.f);
  } else if (t >= 16 && t < 23) {
    const int i = t - 16;
    w2v[b * 7 + i] =
        (red[0][7 + i] + red[1][7 + i] + red[2][7 + i] + red[3][7 + i]) * (1.f / 5376.f);
  }
}

// ---------------- gates: g_h (B,7), g_hw (B,7), g_c (B,768) ----------------
__global__ __launch_bounds__(256) void k_gates(
    const float* __restrict__ h2v, const float* __restrict__ w2v,
    const float* __restrict__ s1v, const float* __restrict__ convH_w,
    const float* __restrict__ convH_b, const float* __restrict__ convH2_k,
    const float* __restrict__ convH2_b, const float* __restrict__ mixhw_k,
    const float* __restrict__ mixhw_b, const float* __restrict__ mixhw2_k,
    const float* __restrict__ mixhw2_b, const float* __restrict__ mixhws_k,
    const float* __restrict__ mixhws_b, const float* __restrict__ mixhws2_k,
    const float* __restrict__ mixhws2_b, const float* __restrict__ linHW,
    const float* __restrict__ linHb, const float* __restrict__ linWW,
    const float* __restrict__ linWb, float* __restrict__ g_h,
    float* __restrict__ g_hw, float* __restrict__ g_c) {
  const int b = blockIdx.x, t = threadIdx.x;
  __shared__ float hv[7], wv[7];
  __shared__ float tc[770];
  if (t < 7) { hv[t] = h2v[b * 7 + t]; wv[t] = w2v[b * 7 + t]; }
  if (t == 7) { tc[0] = 0.f; tc[769] = 0.f; }
  __syncthreads();

  if (t < 7) {
    const float cw = convH_w[0], cbv = convH_b[0];
    const float k0 = convH2_k[0], k1 = convH2_k[1], k2 = convH2_k[2], b2 = convH2_b[0];
    const float um = t > 0 ? sigm(hv[t - 1] * cw + cbv) : 0.f;
    const float u0 = sigm(hv[t] * cw + cbv);
    const float up = t < 6 ? sigm(hv[t + 1] * cw + cbv) : 0.f;
    g_h[b * 7 + t] = sigm(k0 * um + k1 * u0 + k2 * up + b2);

    const float a0 = mixhw_k[0], a1 = mixhw_k[1], ab = mixhw_b[0];
    const float q0 = mixhw2_k[0], q1 = mixhw2_k[1], q2 = mixhw2_k[2], qb = mixhw2_b[0];
    const float vm = t > 0 ? sigm(a0 * hv[t - 1] + a1 * wv[t - 1] + ab) : 0.f;
    const float v0 = sigm(a0 * hv[t] + a1 * wv[t] + ab);
    const float vp = t < 6 ? sigm(a0 * hv[t + 1] + a1 * wv[t + 1] + ab) : 0.f;
    g_hw[b * 7 + t] = sigm(q0 * vm + q1 * v0 + q2 * vp + qb);
  }

  const float m0 = mixhws_k[0], m1 = mixhws_k[1], m2 = mixhws_k[2], mb = mixhws_b[0];
#pragma unroll
  for (int j = 0; j < 3; ++j) {
    const int c = t + j * 256;
    float h2l = linHb[c], w2l = linWb[c];
#pragma unroll
    for (int i = 0; i < 7; ++i) {
      h2l += hv[i] * linHW[c * 7 + i];
      w2l += wv[i] * linWW[c * 7 + i];
    }
    tc[1 + c] = sigm(m0 * h2l + m1 * w2l + m2 * s1v[b * 768 + c] + mb);
  }
  __syncthreads();
  const float r0 = mixhws2_k[0], r1 = mixhws2_k[1], r2 = mixhws2_k[2], rb2 = mixhws2_b[0];
#pragma unroll
  for (int j = 0; j < 3; ++j) {
    const int c = t + j * 256;
    g_c[b * 768 + c] = sigm(r0 * tc[c] + r1 * tc[c + 1] + r2 * tc[c + 2] + rb2);
  }
}

// ---------------- apply gates in place on hws ----------------
__global__ __launch_bounds__(256) void k_gapply(__bf16* __restrict__ hws,
                                                const float* __restrict__ g_h,
                                                const float* __restrict__ g_hw,
                                                const float* __restrict__ g_c) {
  const int idx = blockIdx.x * 256 + threadIdx.x;  // chunk of 8 bf16
  const int k8 = idx % 288;
  const int p = idx / 288;
  const int b = p / 49, pp = p % 49;
  bf16x8* ptr = (bf16x8*)hws + idx;
  bf16x8 v = *ptr;
  if (k8 < 96) {
    const float g = g_h[b * 7 + pp / 7];
#pragma unroll
    for (int e = 0; e < 8; ++e) v[e] = (__bf16)((float)v[e] * g);
  } else if (k8 < 192) {
    const float g = g_hw[b * 7 + pp % 7];
#pragma unroll
    for (int e = 0; e < 8; ++e) v[e] = (__bf16)((float)v[e] * g);
  } else {
    const float* gcp = g_c + b * 768 + (k8 - 192) * 8;
#pragma unroll
    for (int e = 0; e < 8; ++e) v[e] = (__bf16)((float)v[e] * gcp[e]);
  }
  *ptr = v;
}

// ---------------- launch ----------------
extern "C" void kernel_launch(void* const* d_in, const int* in_sizes, int n_in,
                              void* d_out, int out_size, void* d_ws, size_t ws_size,
                              hipStream_t stream) {
  const float* x        = (const float*)d_in[0];
  const float* Wh       = (const float*)d_in[1];
  const float* bh       = (const float*)d_in[2];
  const float* Ww       = (const float*)d_in[3];
  const float* bw       = (const float*)d_in[4];
  const float* Ws       = (const float*)d_in[5];
  const float* bs       = (const float*)d_in[6];
  const float* convH_w  = (const float*)d_in[7];
  const float* convH_b  = (const float*)d_in[8];
  const float* convH2_k = (const float*)d_in[9];
  const float* convH2_b = (const float*)d_in[10];
  const float* mixhw_k  = (const float*)d_in[11];
  const float* mixhw_b  = (const float*)d_in[12];
  const float* mixhw2_k = (const float*)d_in[13];
  const float* mixhw2_b = (const float*)d_in[14];
  const float* mixhws_k = (const float*)d_in[15];
  const float* mixhws_b = (const float*)d_in[16];
  const float* mixhws2_k= (const float*)d_in[17];
  const float* mixhws2_b= (const float*)d_in[18];
  const float* linHW    = (const float*)d_in[19];
  const float* linHb    = (const float*)d_in[20];
  const float* linWW    = (const float*)d_in[21];
  const float* linWb    = (const float*)d_in[22];
  const float* mixallW  = (const float*)d_in[23];
  const float* mixallb  = (const float*)d_in[24];
  const float* projW    = (const float*)d_in[25];
  const float* projb    = (const float*)d_in[26];
  const float* gatew    = (const float*)d_in[27];
  float* out = (float*)d_out;
  (void)in_sizes; (void)n_in; (void)out_size; (void)ws_size;

  const int M = 25088;  // 512*7*7
  char* ws = (char*)d_ws;
  size_t off = 0;
  auto carve = [&](size_t bytes) -> void* {
    void* p = ws + off;
    off += (bytes + 255) & ~(size_t)255;
    return p;
  };
  __bf16* xb     = (__bf16*)carve((size_t)M * 768 * 2);
  __bf16* Wcat   = (__bf16*)carve((size_t)2304 * 768 * 2);
  __bf16* Pb     = (__bf16*)carve((size_t)768 * 768 * 2);
  __bf16* Dt     = (__bf16*)carve((size_t)2304 * 768 * 2);
  __bf16* W2     = (__bf16*)carve((size_t)768 * 2304 * 2);
  float*  bcat   = (float*)carve(2304 * 4);
  float*  b2     = (float*)carve(768 * 4);
  __bf16* hws    = (__bf16*)carve((size_t)M * 2304 * 2);
  float*  h2v    = (float*)carve(512 * 7 * 4);
  float*  w2v    = (float*)carve(512 * 7 * 4);
  float*  s1v    = (float*)carve(512 * 768 * 4);
  float*  gh     = (float*)carve(512 * 7 * 4);
  float*  ghw    = (float*)carve(512 * 7 * 4);
  float*  gc     = (float*)carve(512 * 768 * 4);

  k_convert<<<9408, 256, 0, stream>>>(x, xb, (M * 768) / 8);
  k_convert<<<288, 256, 0, stream>>>(Wh, Wcat, 73728);
  k_convert<<<288, 256, 0, stream>>>(Ww, Wcat + 589824, 73728);
  k_convert<<<288, 256, 0, stream>>>(Ws, Wcat + 1179648, 73728);
  k_convert<<<288, 256, 0, stream>>>(projW, Pb, 73728);
  k_transpose_cvt<<<dim3(72, 24), dim3(32, 8), 0, stream>>>(mixallW, Dt, 768, 2304);
  k_bcat<<<9, 256, 0, stream>>>(bh, bw, bs, bcat);
  k_b2<<<3, 256, 0, stream>>>(projW, mixallb, projb, b2);

  // W2 = P . D : (768 x 2304), K=768
  k_gemm<3, 0><<<3 * 18, 256, 0, stream>>>(Pb, Dt, nullptr, W2, nullptr, nullptr,
                                           nullptr, 2304, 768);
  // [h|w|s] = gelu(x @ [Wh|Ww|Ws]^T + bcat)   (M x 2304, K=768)
  k_gemm<0, 0><<<98 * 18, 256, 0, stream>>>(xb, Wcat, bcat, hws, nullptr, nullptr,
                                            nullptr, 2304, 768);
  k_pool<<<512, 256, 0, stream>>>(hws, h2v, w2v, s1v);
  k_gates<<<512, 256, 0, stream>>>(h2v, w2v, s1v, convH_w, convH_b, convH2_k,
                                   convH2_b, mixhw_k, mixhw_b, mixhw2_k, mixhw2_b,
                                   mixhws_k, mixhws_b, mixhws2_k, mixhws2_b,
                                   linHW, linHb, linWW, linWb, gh, ghw, gc);
  k_gapply<<<28224, 256, 0, stream>>>(hws, gh, ghw, gc);
  // out = g0*(cat @ W2^T + b2) + g1*x  (M x 768, K=2304) — 128-tile, 2-wave, 3 blk/CU
  k_gemm<2, 1><<<196 * 6, 128, 0, stream>>>(hws, W2, b2, nullptr, out, x,
                                            gatew, 768, 2304);
}